// Round 17
// baseline (130.781 us; speedup 1.0000x reference)
//
#include <hip/hip_runtime.h>

typedef unsigned short u16;
typedef __attribute__((ext_vector_type(8))) short bf16x8;
typedef __attribute__((ext_vector_type(4))) float f32x4;
typedef __attribute__((ext_vector_type(4))) unsigned short u16x4;
typedef __attribute__((ext_vector_type(8))) unsigned short u16x8;

#define LOG2E 1.4426950408889634f

__device__ __forceinline__ float bf2f(u16 v) {
    union { unsigned u; float f; } x; x.u = ((unsigned)v) << 16; return x.f;
}
__device__ __forceinline__ u16 f2bf(float f) {
    union { float f; unsigned u; } x; x.f = f;
    unsigned u = x.u;
    u += 0x7FFFu + ((u >> 16) & 1u);   // round-to-nearest-even
    return (u16)(u >> 16);
}
__device__ __forceinline__ float sigm(float x) {
    return __builtin_amdgcn_rcpf(1.f + __builtin_amdgcn_exp2f(-x * LOG2E));
}
__device__ __forceinline__ float tanh_fast(float y) {
    float e = __builtin_amdgcn_exp2f(y * (2.f * LOG2E));
    return 1.f - 2.f * __builtin_amdgcn_rcpf(e + 1.f);   // saturates to +-1 safely
}
// raw barrier: LDS visibility only, NO vmem drain
#define STEP_BAR() asm volatile("s_waitcnt lgkmcnt(0)\ns_barrier" ::: "memory")

// ---------------------------------------------------------------------------
// K1M: fused {attention lower-half} + {weight-fold k0}.
// blocks 0..255   : attention (b = blk>>5, 4 q each; 1024 thr = qq,sh,d)
// blocks 256..447 : Wf/Bf fold (bk = blk-256: z = bk/96, n0 = (bk%96)*4;
//                   thread (i = tid>>8 row, j = tid&255 col))
//   Wf[z][n][j] = bf16(sum_k wih[n][k] cw[k][j])
//   Bf[z][n]    = bih[n] + sum_j wih[n][j] cb[j] + sum_{j>=128} bf16(Wf[n][j])
//   (upper-half attention output == 1.0 exactly -> folded into bias)
// ---------------------------------------------------------------------------
__global__ __launch_bounds__(1024)
void k1m(const float* __restrict__ x, const float* __restrict__ ts,
         const float* __restrict__ qy, const float* __restrict__ bww,
         const float* __restrict__ wihf, const float* __restrict__ bihf,
         const float* __restrict__ wihb, const float* __restrict__ bihb,
         const float* __restrict__ cw, const float* __restrict__ cb,
         u16* __restrict__ aout, u16* __restrict__ Wf, float* __restrict__ Bf)
{
    __shared__ float red[2][4][128];
    __shared__ float red0[4][256];
    const int tid = threadIdx.x;

    if (blockIdx.x < 256) {
        // ---------------- attention ----------------
        const int b  = blockIdx.x >> 5;
        const int q0 = (blockIdx.x & 31) * 4;
        const int d  = tid & 127;
        const int sh = (tid >> 7) & 1;
        const int qq = tid >> 8;

        float w  = bww[d];
        float kk = log1pf(expf(w)) * LOG2E;
        float qv = qy[q0 + qq];
        float A  = -kk * qv * qv, B = 2.f * kk * qv, C = -kk;

        const float* xb = x + (size_t)b * 512 * 256;
        const float* tb = ts + b * 512;

        float num = 0.f, den = 0.f;
        const int s0 = sh * 256;
        #pragma unroll 4
        for (int s = s0; s < s0 + 256; s++) {
            float xv = xb[(size_t)s * 256 + d];
            float mv = xb[(size_t)s * 256 + 128 + d];
            float t  = tb[s];
            float p  = __builtin_amdgcn_exp2f(A + t * (B + C * t));
            num += p * (mv * xv);
            den += p * mv;
        }
        if (sh == 1) { red[0][qq][d] = num; red[1][qq][d] = den; }
        __syncthreads();
        if (sh == 0) {
            num += red[0][qq][d];
            den += red[1][qq][d];
            aout[(size_t)(b * 128 + q0 + qq) * 128 + d] = f2bf(num / fmaxf(den, 1e-30f));
        }
    } else {
        // ---------------- weight fold ----------------
        const int bk = blockIdx.x - 256;
        const int z  = bk / 96;
        const int n0 = (bk % 96) * 4;
        const int i  = tid >> 8;       // row 0..3
        const int j  = tid & 255;
        const float* W   = z ? wihb : wihf;
        const float* bih = z ? bihb : bihf;

        float a = 0.f;
        const float* wr = W + (size_t)(n0 + i) * 256;
        for (int k = 0; k < 256; k++)
            a += wr[k] * cw[(size_t)k * 256 + j];
        u16 wb = f2bf(a);
        Wf[((size_t)z * 384 + n0 + i) * 256 + j] = wb;

        float up = (j >= 128) ? bf2f(wb) : 0.f;
        red0[i][j] = wr[j] * cb[j] + up;
        __syncthreads();
        if (j < 64) red0[i][j] += red0[i][j + 64] + red0[i][j + 128] + red0[i][j + 192];
        __syncthreads();
        if (j == 0) {
            float s = 0.f;
            for (int t2 = 0; t2 < 64; t2++) s += red0[i][t2];
            Bf[z * 384 + n0 + i] = s + bih[n0 + i];
        }
    }
}

// ---------------------------------------------------------------------------
// K3M: fused {xp GEMM slice} + {GRU recurrence} per block.
// 16 blocks = (z, b), 512 thr (8 waves).
// PROLOGUE: wave w computes m-tile w (taus w*16..+15) x 24 n-tiles of
//   xp = aout @ Wf[:,0:128]^T + Bf  -> stores its slice of XP3 (global,
//   L2-local). __syncthreads() (vmcnt drain) publishes it block-wide.
// RECURRENCE: r15 structure -- broadcast A-frag ds_read, 12 chained MFMA
//   per wave (n-tile triple {w,w+8,w+16}), gate on lanes<16, one raw
//   barrier/step, chunked ushort8 xp prefetch.
// ---------------------------------------------------------------------------
__global__ __launch_bounds__(512)
void k3m(const u16* __restrict__ aout,
         const u16* __restrict__ Wf, const float* __restrict__ Bf,
         const float* __restrict__ whf, const float* __restrict__ bhf,
         const float* __restrict__ whb, const float* __restrict__ bhb,
         u16* __restrict__ xp3,        // [2][3][128][8][128] bf16
         u16* __restrict__ hout)       // [2][8][128][128] bf16
{
    const int z   = blockIdx.x >> 3;
    const int b   = blockIdx.x & 7;
    const int tid = threadIdx.x;
    const int w   = tid >> 6;
    const int l   = tid & 63;
    const int nr  = l & 15;
    const int kb  = (l >> 4) * 8;
    const int gdim = w * 16 + (l & 15);       // gate hidden dim (valid l<16)

    __shared__ __align__(16) u16 hist[2][128];   // [slot][hidden] 512 B

    // ---- prologue: xp slice GEMM ----
    {
        const u16* arow = aout + (size_t)(b * 128 + w * 16 + nr) * 128 + kb;
        bf16x8 a0 = *(const bf16x8*)(arow);
        bf16x8 a1 = *(const bf16x8*)(arow + 32);
        bf16x8 a2 = *(const bf16x8*)(arow + 64);
        bf16x8 a3 = *(const bf16x8*)(arow + 96);
        const u16*   Wz = Wf + (size_t)z * 384 * 256;
        const float* Bv = Bf + z * 384;
        u16* xpz = xp3 + (size_t)z * 393216;
        const int t0 = w * 16 + (l >> 4) * 4;
        #pragma unroll 4
        for (int nt = 0; nt < 24; nt++) {
            const u16* brow = Wz + (size_t)(nt * 16 + nr) * 256 + kb;
            f32x4 acc = {0.f, 0.f, 0.f, 0.f};
            acc = __builtin_amdgcn_mfma_f32_16x16x32_bf16(a0, *(const bf16x8*)(brow),      acc, 0,0,0);
            acc = __builtin_amdgcn_mfma_f32_16x16x32_bf16(a1, *(const bf16x8*)(brow + 32), acc, 0,0,0);
            acc = __builtin_amdgcn_mfma_f32_16x16x32_bf16(a2, *(const bf16x8*)(brow + 64), acc, 0,0,0);
            acc = __builtin_amdgcn_mfma_f32_16x16x32_bf16(a3, *(const bf16x8*)(brow + 96), acc, 0,0,0);
            int col = nt * 16 + nr;
            float bias = Bv[col];
            int g  = col >> 7;
            int dv = col & 127;
            size_t base = ((size_t)(g * 128 + dv) * 8 + b) * 128;
            u16 v0 = f2bf(acc[0] + bias), v1 = f2bf(acc[1] + bias);
            u16 v2 = f2bf(acc[2] + bias), v3 = f2bf(acc[3] + bias);
            if (z == 0) {
                u16x4 pv = {v0, v1, v2, v3};
                *(u16x4*)&xpz[base + t0] = pv;
            } else {
                u16x4 pv = {v3, v2, v1, v0};
                *(u16x4*)&xpz[base + 124 - t0] = pv;
            }
        }
    }

    // ---- W_hh B-frags (bf16) in VGPRs: wave w owns n-tiles {w, w+8, w+16} ----
    const float* W  = z ? whb : whf;
    const float* bh = z ? bhb : bhf;
    bf16x8 Whi[3][4];
    #pragma unroll
    for (int g = 0; g < 3; g++) {
        #pragma unroll
        for (int kt = 0; kt < 4; kt++) {
            const float* src = W + (size_t)(g * 128 + w * 16 + nr) * 128 + kt * 32 + kb;
            float4 w0 = *(const float4*)src;
            float4 w1 = *(const float4*)(src + 4);
            bf16x8 hi;
            hi[0] = (short)f2bf(w0.x); hi[1] = (short)f2bf(w0.y);
            hi[2] = (short)f2bf(w0.z); hi[3] = (short)f2bf(w0.w);
            hi[4] = (short)f2bf(w1.x); hi[5] = (short)f2bf(w1.y);
            hi[6] = (short)f2bf(w1.z); hi[7] = (short)f2bf(w1.w);
            Whi[g][kt] = hi;
        }
    }
    if (tid < 128) ((unsigned*)hist)[tid] = 0u;    // h = 0 (both slots)
    __syncthreads();   // drains vmcnt -> xp3 slice visible block-wide

    float br = 0.f, bz = 0.f, bn = 0.f;
    float hm = 0.f;
    const u16* xq = xp3 + (size_t)z * 393216;
    u16* ho = hout + (size_t)z * 131072 + (size_t)b * 16384;

    // chunked xp prefetch (gate lanes only)
    size_t bR = 0, bZ = 0, bN = 0;
    u16x8 cR = {0,0,0,0,0,0,0,0}, cZ = cR, cN = cR;
    u16x8 nR = cR, nZ = cR, nN = cR;
    if (l < 16) {
        br = bh[gdim]; bz = bh[gdim + 128]; bn = bh[gdim + 256];
        bR = ((size_t)(0 * 128 + gdim) * 8 + b) * 128;
        bZ = ((size_t)(1 * 128 + gdim) * 8 + b) * 128;
        bN = ((size_t)(2 * 128 + gdim) * 8 + b) * 128;
        cR = *(const u16x8*)&xq[bR];      cZ = *(const u16x8*)&xq[bZ];      cN = *(const u16x8*)&xq[bN];
        nR = *(const u16x8*)&xq[bR + 8];  nZ = *(const u16x8*)&xq[bZ + 8];  nN = *(const u16x8*)&xq[bN + 8];
    }

    const f32x4 z4 = {0.f, 0.f, 0.f, 0.f};

    for (int ch = 0; ch < 16; ch++) {
        #pragma unroll
        for (int s = 0; s < 8; s++) {
            const int c = ch * 8 + s;
            const int rslot = (c + 1) & 1, wslot = c & 1;

            // broadcast A-frag read (16-lane groups share an address)
            const u16* hb_ = &hist[rslot][kb];
            bf16x8 A0 = *(const bf16x8*)&hb_[0];
            bf16x8 A1 = *(const bf16x8*)&hb_[32];
            bf16x8 A2 = *(const bf16x8*)&hb_[64];
            bf16x8 A3 = *(const bf16x8*)&hb_[96];

            f32x4 a0 = z4, a1 = z4, a2 = z4;
            a0 = __builtin_amdgcn_mfma_f32_16x16x32_bf16(A0, Whi[0][0], a0, 0,0,0);
            a1 = __builtin_amdgcn_mfma_f32_16x16x32_bf16(A0, Whi[1][0], a1, 0,0,0);
            a2 = __builtin_amdgcn_mfma_f32_16x16x32_bf16(A0, Whi[2][0], a2, 0,0,0);
            a0 = __builtin_amdgcn_mfma_f32_16x16x32_bf16(A1, Whi[0][1], a0, 0,0,0);
            a1 = __builtin_amdgcn_mfma_f32_16x16x32_bf16(A1, Whi[1][1], a1, 0,0,0);
            a2 = __builtin_amdgcn_mfma_f32_16x16x32_bf16(A1, Whi[2][1], a2, 0,0,0);
            a0 = __builtin_amdgcn_mfma_f32_16x16x32_bf16(A2, Whi[0][2], a0, 0,0,0);
            a1 = __builtin_amdgcn_mfma_f32_16x16x32_bf16(A2, Whi[1][2], a1, 0,0,0);
            a2 = __builtin_amdgcn_mfma_f32_16x16x32_bf16(A2, Whi[2][2], a2, 0,0,0);
            a0 = __builtin_amdgcn_mfma_f32_16x16x32_bf16(A3, Whi[0][3], a0, 0,0,0);
            a1 = __builtin_amdgcn_mfma_f32_16x16x32_bf16(A3, Whi[1][3], a1, 0,0,0);
            a2 = __builtin_amdgcn_mfma_f32_16x16x32_bf16(A3, Whi[2][3], a2, 0,0,0);

            if (l < 16) {
                const int tw = z ? (127 - c) : c;
                float rr = sigm(bf2f((u16)cR[s]) + a0[0] + br);
                float zg = sigm(bf2f((u16)cZ[s]) + a1[0] + bz);
                float nn = tanh_fast(bf2f((u16)cN[s]) + rr * (a2[0] + bn));
                hm = (1.f - zg) * nn + zg * hm;
                u16 hb2 = f2bf(hm);
                hist[wslot][gdim] = hb2;
                ho[(size_t)tw * 128 + gdim] = hb2;
            }
            STEP_BAR();
        }
        if (l < 16) {
            cR = nR; cZ = nZ; cN = nN;
            if (ch < 14) {
                const size_t o = (size_t)(ch + 2) * 8;
                nR = *(const u16x8*)&xq[bR + o];
                nZ = *(const u16x8*)&xq[bZ + o];
                nN = *(const u16x8*)&xq[bN + o];
            }
        }
    }
}

// ---------------------------------------------------------------------------
// K4: MLP head. 1024 blocks = (b,t), 128 threads. (unchanged)
// ---------------------------------------------------------------------------
__global__ __launch_bounds__(128)
void k4_mlp(const u16* __restrict__ hout,
            const float* __restrict__ w1, const float* __restrict__ b1,
            const float* __restrict__ w2, const float* __restrict__ b2,
            float* __restrict__ out)
{
    const int bq  = blockIdx.x;
    const int tid = threadIdx.x;

    __shared__ __align__(16) float hrow[256];
    __shared__ float hid[50];

    const u16* hf = hout + (size_t)bq * 128;
    const u16* hb = hout + (size_t)8 * 128 * 128 + (size_t)bq * 128;
    hrow[tid]       = bf2f(hf[tid]);
    hrow[128 + tid] = bf2f(hb[tid]);
    __syncthreads();

    if (tid < 50) {
        float a = b1[tid];
        const float* wr = w1 + (size_t)tid * 256;
        for (int k0 = 0; k0 < 256; k0 += 8) {
            float4 wv0 = *(const float4*)&wr[k0];
            float4 wv1 = *(const float4*)&wr[k0 + 4];
            float4 h0  = *(const float4*)&hrow[k0];
            float4 h1  = *(const float4*)&hrow[k0 + 4];
            a += wv0.x * h0.x + wv0.y * h0.y + wv0.z * h0.z + wv0.w * h0.w;
            a += wv1.x * h1.x + wv1.y * h1.y + wv1.z * h1.z + wv1.w * h1.w;
        }
        hid[tid] = fmaxf(a, 0.f);
    }
    __syncthreads();
    if (tid < 64) {
        float a = b2[tid];
        const float* wr = w2 + (size_t)tid * 50;
        for (int k = 0; k < 50; k++) a += wr[k] * hid[k];
        out[(size_t)bq * 64 + tid] = a;
    }
}

// ---------------------------------------------------------------------------
// Workspace (~2.63 MB), NO aliasing (k3m writes hout while sibling blocks
// may still read aout -> hout gets its own region):
//   [0,      256K) : aout bf16 [1024][128]   (k1m -> k3m)
//   [256K,   768K) : hout bf16 [2][8][128][128] (k3m -> k4)
//   [768K,  1.143M): Wf bf16 [2][384][256]   (k1m -> k3m)
//   [1.143M,+3K)   : Bf f32 [2][384]         (k1m -> k3m)
//   [1.25M, 2.75M) : xp3 bf16 [2][3][128][8][128] (k3m internal)
// ---------------------------------------------------------------------------
extern "C" void kernel_launch(void* const* d_in, const int* in_sizes, int n_in,
                              void* d_out, int out_size, void* d_ws, size_t ws_size,
                              hipStream_t stream)
{
    const float* x    = (const float*)d_in[0];
    const float* ts   = (const float*)d_in[1];
    const float* qy   = (const float*)d_in[2];
    const float* bww  = (const float*)d_in[3];
    const float* cw   = (const float*)d_in[4];
    const float* cb   = (const float*)d_in[5];
    const float* wihf = (const float*)d_in[6];
    const float* whhf = (const float*)d_in[7];
    const float* bihf = (const float*)d_in[8];
    const float* bhhf = (const float*)d_in[9];
    const float* wihb = (const float*)d_in[10];
    const float* whhb = (const float*)d_in[11];
    const float* bihb = (const float*)d_in[12];
    const float* bhhb = (const float*)d_in[13];
    const float* w1   = (const float*)d_in[14];
    const float* b1   = (const float*)d_in[15];
    const float* w2   = (const float*)d_in[16];
    const float* b2   = (const float*)d_in[17];
    float* out = (float*)d_out;

    char* ws = (char*)d_ws;
    u16*   aout = (u16*)ws;                             // 256 KB
    u16*   hout = (u16*)(ws + (256 << 10));             // 512 KB
    u16*   Wf   = (u16*)(ws + (768 << 10));             // 384 KB
    float* Bf   = (float*)(ws + (768 << 10) + 384 * 1024);  // 3 KB
    u16*   xp3  = (u16*)(ws + (1280 << 10));            // 1.5 MB

    k1m<<<448, 1024, 0, stream>>>(x, ts, qy, bww, wihf, bihf, wihb, bihb,
                                  cw, cb, aout, Wf, Bf);
    k3m<<<16, 512, 0, stream>>>(aout, Wf, Bf, whhf, bhhf, whhb, bhhb, xp3, hout);
    k4_mlp<<<1024, 128, 0, stream>>>(hout, w1, b1, w2, b2, out);
}

// Round 18
// 113.521 us; speedup vs baseline: 1.1520x; 1.1520x over previous
//
#include <hip/hip_runtime.h>

typedef unsigned short u16;
typedef __attribute__((ext_vector_type(8))) short bf16x8;
typedef __attribute__((ext_vector_type(4))) float f32x4;
typedef __attribute__((ext_vector_type(4))) unsigned short u16x4;
typedef __attribute__((ext_vector_type(8))) unsigned short u16x8;

#define LOG2E 1.4426950408889634f

__device__ __forceinline__ float bf2f(u16 v) {
    union { unsigned u; float f; } x; x.u = ((unsigned)v) << 16; return x.f;
}
__device__ __forceinline__ u16 f2bf(float f) {
    union { float f; unsigned u; } x; x.f = f;
    unsigned u = x.u;
    u += 0x7FFFu + ((u >> 16) & 1u);   // round-to-nearest-even
    return (u16)(u >> 16);
}
__device__ __forceinline__ float sigm(float x) {
    return __builtin_amdgcn_rcpf(1.f + __builtin_amdgcn_exp2f(-x * LOG2E));
}
__device__ __forceinline__ float tanh_fast(float y) {
    float e = __builtin_amdgcn_exp2f(y * (2.f * LOG2E));
    return 1.f - 2.f * __builtin_amdgcn_rcpf(e + 1.f);   // saturates to +-1 safely
}
// raw barrier: LDS visibility only, NO vmem drain
#define STEP_BAR() asm volatile("s_waitcnt lgkmcnt(0)\ns_barrier" ::: "memory")

// ---------------------------------------------------------------------------
// K0: fold cross projection into GRU input weights + fold constant upper-half
// attention output (== 1.0 exactly) into the bias. (round-16 version)
// ---------------------------------------------------------------------------
__global__ __launch_bounds__(256)
void k0_fuse(const float* __restrict__ wihf, const float* __restrict__ bihf,
             const float* __restrict__ wihb, const float* __restrict__ bihb,
             const float* __restrict__ cw, const float* __restrict__ cb,
             u16* __restrict__ Wf, float* __restrict__ Bf)
{
    const int z  = blockIdx.x / 96;
    const int n0 = (blockIdx.x % 96) * 4;
    const int j  = threadIdx.x;
    const float* W   = z ? wihb : wihf;
    const float* bih = z ? bihb : bihf;

    __shared__ float red[256];

    float av[4] = {0.f, 0.f, 0.f, 0.f};
    for (int k = 0; k < 256; k++) {
        float cv = cw[(size_t)k * 256 + j];
        av[0] += W[(size_t)(n0 + 0) * 256 + k] * cv;
        av[1] += W[(size_t)(n0 + 1) * 256 + k] * cv;
        av[2] += W[(size_t)(n0 + 2) * 256 + k] * cv;
        av[3] += W[(size_t)(n0 + 3) * 256 + k] * cv;
    }
    u16 wb16[4];
    u16* wout = Wf + ((size_t)z * 384 + n0) * 256 + j;
    #pragma unroll
    for (int i = 0; i < 4; i++) {
        wb16[i] = f2bf(av[i]);
        wout[i * 256] = wb16[i];
    }

    float cbv = cb[j];
    #pragma unroll
    for (int i = 0; i < 4; i++) {
        float up = (j >= 128) ? bf2f(wb16[i]) : 0.f;   // upper-half fold (aout==1)
        red[j] = W[(size_t)(n0 + i) * 256 + j] * cbv + up;
        __syncthreads();
        if (j < 64) red[j] += red[j + 64] + red[j + 128] + red[j + 192];
        __syncthreads();
        if (j == 0) {
            float s = 0.f;
            for (int t = 0; t < 64; t++) s += red[t];
            Bf[z * 384 + n0 + i] = s + bih[n0 + i];
        }
        __syncthreads();
    }
}

// ---------------------------------------------------------------------------
// K1: time-kernel attention, LOWER HALF ONLY, zero-LDS main loop.
// (round-16 version)
// ---------------------------------------------------------------------------
__global__ __launch_bounds__(1024)
void k1_attn(const float* __restrict__ x, const float* __restrict__ ts,
             const float* __restrict__ qy, const float* __restrict__ bww,
             u16* __restrict__ aout)     // [1024][128] bf16
{
    const int b   = blockIdx.x >> 5;
    const int q0  = (blockIdx.x & 31) * 4;
    const int tid = threadIdx.x;
    const int d   = tid & 127;
    const int sh  = (tid >> 7) & 1;
    const int qq  = tid >> 8;

    __shared__ float red[2][4][128];

    float w  = bww[d];
    float kk = log1pf(expf(w)) * LOG2E;
    float qv = qy[q0 + qq];
    float A  = -kk * qv * qv, B = 2.f * kk * qv, C = -kk;

    const float* xb = x + (size_t)b * 512 * 256;
    const float* tb = ts + b * 512;

    float num = 0.f, den = 0.f;
    const int s0 = sh * 256;
    #pragma unroll 4
    for (int s = s0; s < s0 + 256; s++) {
        float xv = xb[(size_t)s * 256 + d];
        float mv = xb[(size_t)s * 256 + 128 + d];
        float t  = tb[s];
        float p  = __builtin_amdgcn_exp2f(A + t * (B + C * t));
        num += p * (mv * xv);
        den += p * mv;
    }

    if (sh == 1) { red[0][qq][d] = num; red[1][qq][d] = den; }
    __syncthreads();
    if (sh == 0) {
        num += red[0][qq][d];
        den += red[1][qq][d];
        aout[(size_t)(b * 128 + q0 + qq) * 128 + d] = f2bf(num / fmaxf(den, 1e-30f));
    }
}

// ---------------------------------------------------------------------------
// K2: xp3 = aout @ Wf[:,0:128]^T + Bf via MFMA (K=128). (round-16 version)
// XP3[z][g][dim][b][tau] layout, tau = (z ? 127-t : t).
// ---------------------------------------------------------------------------
__global__ __launch_bounds__(256)
void k2_xp(const u16* __restrict__ aout,
           const u16* __restrict__ Wf, const float* __restrict__ Bf,
           u16* __restrict__ xp3)    // [2][3][128][8][128] bf16
{
    const int wid  = threadIdx.x >> 6;
    const int lane = threadIdx.x & 63;
    int gw = blockIdx.x * 4 + wid;
    int z  = (gw >= 1536) ? 1 : 0;
    int t  = gw - z * 1536;
    int rt = t / 24, nt = t - rt * 24;
    int r0 = rt * 16, n0 = nt * 16;

    const u16*   W  = Wf + (size_t)z * 384 * 256;
    const float* Bv = Bf + z * 384;

    const u16* arow = aout + (size_t)(r0 + (lane & 15)) * 128 + (lane >> 4) * 8;
    const u16* brow = W    + (size_t)(n0 + (lane & 15)) * 256 + (lane >> 4) * 8;

    f32x4 acc = {0.f, 0.f, 0.f, 0.f};
    #pragma unroll
    for (int k = 0; k < 4; k++) {
        bf16x8 a     = *(const bf16x8*)(arow + k * 32);
        bf16x8 bfrag = *(const bf16x8*)(brow + k * 32);
        acc = __builtin_amdgcn_mfma_f32_16x16x32_bf16(a, bfrag, acc, 0, 0, 0);
    }
    int col   = n0 + (lane & 15);
    int rbase = r0 + (lane >> 4) * 4;
    float bias = Bv[col];
    int g   = col >> 7;
    int dv  = col & 127;
    int bb  = rbase >> 7;
    int tt0 = rbase & 127;
    u16* xpz = xp3 + (size_t)z * 393216;
    size_t base = ((size_t)(g * 128 + dv) * 8 + bb) * 128;
    u16 v0 = f2bf(acc[0] + bias), v1 = f2bf(acc[1] + bias);
    u16 v2 = f2bf(acc[2] + bias), v3 = f2bf(acc[3] + bias);
    if (z == 0) {
        u16x4 pv = {v0, v1, v2, v3};
        *(u16x4*)&xpz[base + tt0] = pv;
    } else {
        u16x4 pv = {v3, v2, v1, v0};
        *(u16x4*)&xpz[base + 124 - tt0] = pv;
    }
}

// ---------------------------------------------------------------------------
// K3: bidirectional GRU, round-15 version (best measured: 61.0 us).
// 16 blocks = (z, b), 512 thr (8 waves). Per step: broadcast A-frag ds_read,
// 12 chained MFMA/wave (n-tile triple {w,w+8,w+16}), gate on lanes<16, one
// raw barrier. hist 2-slot ring; chunked ushort8 xp prefetch.
// ---------------------------------------------------------------------------
__global__ __launch_bounds__(512)
void k3_gru(const u16* __restrict__ xp3,      // [2][3][128][8][128] bf16
            const float* __restrict__ whf, const float* __restrict__ bhf,
            const float* __restrict__ whb, const float* __restrict__ bhb,
            u16* __restrict__ hout)           // [2][8][128][128] bf16
{
    const int z   = blockIdx.x >> 3;
    const int b   = blockIdx.x & 7;           // batch
    const int tid = threadIdx.x;
    const int w   = tid >> 6;
    const int l   = tid & 63;
    const int nr  = l & 15;
    const int kb  = (l >> 4) * 8;
    const int gdim = w * 16 + (l & 15);       // gate hidden dim (valid l<16)

    __shared__ __align__(16) u16 hist[2][128];   // [slot][hidden] 512 B

    const float* W  = z ? whb : whf;
    const float* bh = z ? bhb : bhf;

    // W_hh B-frags (bf16) in VGPRs: wave w owns n-tiles {w, w+8, w+16}
    bf16x8 Whi[3][4];
    #pragma unroll
    for (int g = 0; g < 3; g++) {
        #pragma unroll
        for (int kt = 0; kt < 4; kt++) {
            const float* src = W + (size_t)(g * 128 + w * 16 + nr) * 128 + kt * 32 + kb;
            float4 w0 = *(const float4*)src;
            float4 w1 = *(const float4*)(src + 4);
            bf16x8 hi;
            hi[0] = (short)f2bf(w0.x); hi[1] = (short)f2bf(w0.y);
            hi[2] = (short)f2bf(w0.z); hi[3] = (short)f2bf(w0.w);
            hi[4] = (short)f2bf(w1.x); hi[5] = (short)f2bf(w1.y);
            hi[6] = (short)f2bf(w1.z); hi[7] = (short)f2bf(w1.w);
            Whi[g][kt] = hi;
        }
    }

    float br = 0.f, bz = 0.f, bn = 0.f;
    float hm = 0.f;
    const u16* xq = xp3 + (size_t)z * 393216;
    u16* ho = hout + (size_t)z * 131072 + (size_t)b * 16384;

    // chunked xp prefetch (gate lanes only)
    size_t bR = 0, bZ = 0, bN = 0;
    u16x8 cR = {0,0,0,0,0,0,0,0}, cZ = cR, cN = cR;   // current chunk
    u16x8 nR = cR, nZ = cR, nN = cR;                  // next chunk
    if (l < 16) {
        br = bh[gdim]; bz = bh[gdim + 128]; bn = bh[gdim + 256];
        bR = ((size_t)(0 * 128 + gdim) * 8 + b) * 128;
        bZ = ((size_t)(1 * 128 + gdim) * 8 + b) * 128;
        bN = ((size_t)(2 * 128 + gdim) * 8 + b) * 128;
        cR = *(const u16x8*)&xq[bR];      cZ = *(const u16x8*)&xq[bZ];      cN = *(const u16x8*)&xq[bN];
        nR = *(const u16x8*)&xq[bR + 8];  nZ = *(const u16x8*)&xq[bZ + 8];  nN = *(const u16x8*)&xq[bN + 8];
    }
    if (tid < 128) ((unsigned*)hist)[tid] = 0u;    // h = 0 (both slots)
    __syncthreads();

    const f32x4 z4 = {0.f, 0.f, 0.f, 0.f};

    for (int ch = 0; ch < 16; ch++) {
        #pragma unroll
        for (int s = 0; s < 8; s++) {
            const int c = ch * 8 + s;
            const int rslot = (c + 1) & 1, wslot = c & 1;

            // broadcast A-frag read (16-lane groups share an address)
            const u16* hb_ = &hist[rslot][kb];
            bf16x8 A0 = *(const bf16x8*)&hb_[0];
            bf16x8 A1 = *(const bf16x8*)&hb_[32];
            bf16x8 A2 = *(const bf16x8*)&hb_[64];
            bf16x8 A3 = *(const bf16x8*)&hb_[96];

            f32x4 a0 = z4, a1 = z4, a2 = z4;
            a0 = __builtin_amdgcn_mfma_f32_16x16x32_bf16(A0, Whi[0][0], a0, 0,0,0);
            a1 = __builtin_amdgcn_mfma_f32_16x16x32_bf16(A0, Whi[1][0], a1, 0,0,0);
            a2 = __builtin_amdgcn_mfma_f32_16x16x32_bf16(A0, Whi[2][0], a2, 0,0,0);
            a0 = __builtin_amdgcn_mfma_f32_16x16x32_bf16(A1, Whi[0][1], a0, 0,0,0);
            a1 = __builtin_amdgcn_mfma_f32_16x16x32_bf16(A1, Whi[1][1], a1, 0,0,0);
            a2 = __builtin_amdgcn_mfma_f32_16x16x32_bf16(A1, Whi[2][1], a2, 0,0,0);
            a0 = __builtin_amdgcn_mfma_f32_16x16x32_bf16(A2, Whi[0][2], a0, 0,0,0);
            a1 = __builtin_amdgcn_mfma_f32_16x16x32_bf16(A2, Whi[1][2], a1, 0,0,0);
            a2 = __builtin_amdgcn_mfma_f32_16x16x32_bf16(A2, Whi[2][2], a2, 0,0,0);
            a0 = __builtin_amdgcn_mfma_f32_16x16x32_bf16(A3, Whi[0][3], a0, 0,0,0);
            a1 = __builtin_amdgcn_mfma_f32_16x16x32_bf16(A3, Whi[1][3], a1, 0,0,0);
            a2 = __builtin_amdgcn_mfma_f32_16x16x32_bf16(A3, Whi[2][3], a2, 0,0,0);

            if (l < 16) {
                const int tw = z ? (127 - c) : c;
                float rr = sigm(bf2f((u16)cR[s]) + a0[0] + br);
                float zg = sigm(bf2f((u16)cZ[s]) + a1[0] + bz);
                float nn = tanh_fast(bf2f((u16)cN[s]) + rr * (a2[0] + bn));
                hm = (1.f - zg) * nn + zg * hm;
                u16 hb2 = f2bf(hm);
                hist[wslot][gdim] = hb2;
                ho[(size_t)tw * 128 + gdim] = hb2;
            }
            STEP_BAR();
        }
        // chunk boundary: rotate and issue loads for chunk ch+2
        if (l < 16) {
            cR = nR; cZ = nZ; cN = nN;
            if (ch < 14) {
                const size_t o = (size_t)(ch + 2) * 8;
                nR = *(const u16x8*)&xq[bR + o];
                nZ = *(const u16x8*)&xq[bZ + o];
                nN = *(const u16x8*)&xq[bN + o];
            }
        }
    }
}

// ---------------------------------------------------------------------------
// K4: MLP head. 1024 blocks = (b,t), 128 threads. (unchanged)
// ---------------------------------------------------------------------------
__global__ __launch_bounds__(128)
void k4_mlp(const u16* __restrict__ hout,
            const float* __restrict__ w1, const float* __restrict__ b1,
            const float* __restrict__ w2, const float* __restrict__ b2,
            float* __restrict__ out)
{
    const int bq  = blockIdx.x;
    const int tid = threadIdx.x;

    __shared__ __align__(16) float hrow[256];
    __shared__ float hid[50];

    const u16* hf = hout + (size_t)bq * 128;
    const u16* hb = hout + (size_t)8 * 128 * 128 + (size_t)bq * 128;
    hrow[tid]       = bf2f(hf[tid]);
    hrow[128 + tid] = bf2f(hb[tid]);
    __syncthreads();

    if (tid < 50) {
        float a = b1[tid];
        const float* wr = w1 + (size_t)tid * 256;
        for (int k0 = 0; k0 < 256; k0 += 8) {
            float4 wv0 = *(const float4*)&wr[k0];
            float4 wv1 = *(const float4*)&wr[k0 + 4];
            float4 h0  = *(const float4*)&hrow[k0];
            float4 h1  = *(const float4*)&hrow[k0 + 4];
            a += wv0.x * h0.x + wv0.y * h0.y + wv0.z * h0.z + wv0.w * h0.w;
            a += wv1.x * h1.x + wv1.y * h1.y + wv1.z * h1.z + wv1.w * h1.w;
        }
        hid[tid] = fmaxf(a, 0.f);
    }
    __syncthreads();
    if (tid < 64) {
        float a = b2[tid];
        const float* wr = w2 + (size_t)tid * 50;
        for (int k = 0; k < 50; k++) a += wr[k] * hid[k];
        out[(size_t)bq * 64 + tid] = a;
    }
}

// ---------------------------------------------------------------------------
// Workspace (2.4 MB):
//   [0,     512K)  : aout bf16 [1024][128] (K1->K2), reused as hout (K3->K4)
//   [512K,  2.0M)  : xp3 bf16 (K2->K3, tau-innermost layout)
//   [2.0M,  2.375M): Wf bf16 [2][384][256] (K0->K2)
//   [2.375M,+3K)   : Bf f32  [2][384]      (K0->K2, upper-half folded)
// ---------------------------------------------------------------------------
extern "C" void kernel_launch(void* const* d_in, const int* in_sizes, int n_in,
                              void* d_out, int out_size, void* d_ws, size_t ws_size,
                              hipStream_t stream)
{
    const float* x    = (const float*)d_in[0];
    const float* ts   = (const float*)d_in[1];
    const float* qy   = (const float*)d_in[2];
    const float* bww  = (const float*)d_in[3];
    const float* cw   = (const float*)d_in[4];
    const float* cb   = (const float*)d_in[5];
    const float* wihf = (const float*)d_in[6];
    const float* whhf = (const float*)d_in[7];
    const float* bihf = (const float*)d_in[8];
    const float* bhhf = (const float*)d_in[9];
    const float* wihb = (const float*)d_in[10];
    const float* whhb = (const float*)d_in[11];
    const float* bihb = (const float*)d_in[12];
    const float* bhhb = (const float*)d_in[13];
    const float* w1   = (const float*)d_in[14];
    const float* b1   = (const float*)d_in[15];
    const float* w2   = (const float*)d_in[16];
    const float* b2   = (const float*)d_in[17];
    float* out = (float*)d_out;

    char* ws = (char*)d_ws;
    u16*   aout = (u16*)ws;                            // 256 KB used
    u16*   hout = (u16*)ws;                            // alias (aout dead after K2)
    u16*   xp3  = (u16*)(ws + (512 << 10));            // 1.5 MB
    u16*   Wf   = (u16*)(ws + (2u << 20));             // 384 KB
    float* Bf   = (float*)(ws + (2u << 20) + 384 * 1024);  // 3 KB

    k0_fuse<<<192, 256, 0, stream>>>(wihf, bihf, wihb, bihb, cw, cb, Wf, Bf);
    k1_attn<<<256, 1024, 0, stream>>>(x, ts, qy, bww, aout);
    k2_xp<<<768, 256, 0, stream>>>(aout, Wf, Bf, xp3);
    k3_gru<<<16, 512, 0, stream>>>(xp3, whhf, bhhf, whhb, bhhb, hout);
    k4_mlp<<<1024, 128, 0, stream>>>(hout, w1, b1, w2, b2, out);
}

// Round 19
// 113.259 us; speedup vs baseline: 1.1547x; 1.0023x over previous
//
#include <hip/hip_runtime.h>

typedef unsigned short u16;
typedef __attribute__((ext_vector_type(8))) short bf16x8;
typedef __attribute__((ext_vector_type(4))) float f32x4;
typedef __attribute__((ext_vector_type(4))) unsigned short u16x4;
typedef __attribute__((ext_vector_type(8))) unsigned short u16x8;

#define LOG2E 1.4426950408889634f

__device__ __forceinline__ float bf2f(u16 v) {
    union { unsigned u; float f; } x; x.u = ((unsigned)v) << 16; return x.f;
}
__device__ __forceinline__ u16 f2bf(float f) {
    union { float f; unsigned u; } x; x.f = f;
    unsigned u = x.u;
    u += 0x7FFFu + ((u >> 16) & 1u);   // round-to-nearest-even
    return (u16)(u >> 16);
}
__device__ __forceinline__ float sigm(float x) {
    return __builtin_amdgcn_rcpf(1.f + __builtin_amdgcn_exp2f(-x * LOG2E));
}
__device__ __forceinline__ float tanh_fast(float y) {
    float e = __builtin_amdgcn_exp2f(y * (2.f * LOG2E));
    return 1.f - 2.f * __builtin_amdgcn_rcpf(e + 1.f);   // saturates to +-1 safely
}
// raw barrier: LDS visibility only, NO vmem drain
#define STEP_BAR() asm volatile("s_waitcnt lgkmcnt(0)\ns_barrier" ::: "memory")

// ---------------------------------------------------------------------------
// K1M: fused {attention lower-half} + {weight-fold}.  (r17's k1m -- the
// fusion that worked; r17's regression was the k3m GEMM-on-16-CUs, not this.)
// blocks 0..255   : attention (b = blk>>5, 4 q each; 1024 thr = qq,sh,d)
// blocks 256..447 : Wf/Bf fold (bk = blk-256: z = bk/96, n0 = (bk%96)*4;
//                   thread (i = tid>>8 row, j = tid&255 col))
//   Wf[z][n][j] = bf16(sum_k wih[n][k] cw[k][j])
//   Bf[z][n]    = bih[n] + sum_j wih[n][j] cb[j] + sum_{j>=128} bf16(Wf[n][j])
//   (upper-half attention output == 1.0 exactly -> folded into bias)
// ---------------------------------------------------------------------------
__global__ __launch_bounds__(1024)
void k1m(const float* __restrict__ x, const float* __restrict__ ts,
         const float* __restrict__ qy, const float* __restrict__ bww,
         const float* __restrict__ wihf, const float* __restrict__ bihf,
         const float* __restrict__ wihb, const float* __restrict__ bihb,
         const float* __restrict__ cw, const float* __restrict__ cb,
         u16* __restrict__ aout, u16* __restrict__ Wf, float* __restrict__ Bf)
{
    __shared__ float red[2][4][128];
    __shared__ float red0[4][256];
    const int tid = threadIdx.x;

    if (blockIdx.x < 256) {
        // ---------------- attention (lower half only) ----------------
        const int b  = blockIdx.x >> 5;
        const int q0 = (blockIdx.x & 31) * 4;
        const int d  = tid & 127;
        const int sh = (tid >> 7) & 1;
        const int qq = tid >> 8;

        float w  = bww[d];
        float kk = log1pf(expf(w)) * LOG2E;
        float qv = qy[q0 + qq];
        float A  = -kk * qv * qv, B = 2.f * kk * qv, C = -kk;

        const float* xb = x + (size_t)b * 512 * 256;
        const float* tb = ts + b * 512;

        float num = 0.f, den = 0.f;
        const int s0 = sh * 256;
        #pragma unroll 4
        for (int s = s0; s < s0 + 256; s++) {
            float xv = xb[(size_t)s * 256 + d];
            float mv = xb[(size_t)s * 256 + 128 + d];
            float t  = tb[s];
            float p  = __builtin_amdgcn_exp2f(A + t * (B + C * t));
            num += p * (mv * xv);
            den += p * mv;
        }
        if (sh == 1) { red[0][qq][d] = num; red[1][qq][d] = den; }
        __syncthreads();
        if (sh == 0) {
            num += red[0][qq][d];
            den += red[1][qq][d];
            aout[(size_t)(b * 128 + q0 + qq) * 128 + d] = f2bf(num / fmaxf(den, 1e-30f));
        }
    } else {
        // ---------------- weight fold ----------------
        const int bk = blockIdx.x - 256;
        const int z  = bk / 96;
        const int n0 = (bk % 96) * 4;
        const int i  = tid >> 8;       // row 0..3
        const int j  = tid & 255;
        const float* W   = z ? wihb : wihf;
        const float* bih = z ? bihb : bihf;

        float a = 0.f;
        const float* wr = W + (size_t)(n0 + i) * 256;
        for (int k = 0; k < 256; k++)
            a += wr[k] * cw[(size_t)k * 256 + j];
        u16 wb = f2bf(a);
        Wf[((size_t)z * 384 + n0 + i) * 256 + j] = wb;

        float up = (j >= 128) ? bf2f(wb) : 0.f;
        red0[i][j] = wr[j] * cb[j] + up;
        __syncthreads();
        if (j < 64) red0[i][j] += red0[i][j + 64] + red0[i][j + 128] + red0[i][j + 192];
        __syncthreads();
        if (j == 0) {
            float s = 0.f;
            for (int t2 = 0; t2 < 64; t2++) s += red0[i][t2];
            Bf[z * 384 + n0 + i] = s + bih[n0 + i];
        }
    }
}

// ---------------------------------------------------------------------------
// K2: xp3 = aout @ Wf[:,0:128]^T + Bf via MFMA (K=128). (r16/r18 version)
// XP3[z][g][dim][b][tau] layout, tau = (z ? 127-t : t).
// ---------------------------------------------------------------------------
__global__ __launch_bounds__(256)
void k2_xp(const u16* __restrict__ aout,
           const u16* __restrict__ Wf, const float* __restrict__ Bf,
           u16* __restrict__ xp3)    // [2][3][128][8][128] bf16
{
    const int wid  = threadIdx.x >> 6;
    const int lane = threadIdx.x & 63;
    int gw = blockIdx.x * 4 + wid;
    int z  = (gw >= 1536) ? 1 : 0;
    int t  = gw - z * 1536;
    int rt = t / 24, nt = t - rt * 24;
    int r0 = rt * 16, n0 = nt * 16;

    const u16*   W  = Wf + (size_t)z * 384 * 256;
    const float* Bv = Bf + z * 384;

    const u16* arow = aout + (size_t)(r0 + (lane & 15)) * 128 + (lane >> 4) * 8;
    const u16* brow = W    + (size_t)(n0 + (lane & 15)) * 256 + (lane >> 4) * 8;

    f32x4 acc = {0.f, 0.f, 0.f, 0.f};
    #pragma unroll
    for (int k = 0; k < 4; k++) {
        bf16x8 a     = *(const bf16x8*)(arow + k * 32);
        bf16x8 bfrag = *(const bf16x8*)(brow + k * 32);
        acc = __builtin_amdgcn_mfma_f32_16x16x32_bf16(a, bfrag, acc, 0, 0, 0);
    }
    int col   = n0 + (lane & 15);
    int rbase = r0 + (lane >> 4) * 4;
    float bias = Bv[col];
    int g   = col >> 7;
    int dv  = col & 127;
    int bb  = rbase >> 7;
    int tt0 = rbase & 127;
    u16* xpz = xp3 + (size_t)z * 393216;
    size_t base = ((size_t)(g * 128 + dv) * 8 + bb) * 128;
    u16 v0 = f2bf(acc[0] + bias), v1 = f2bf(acc[1] + bias);
    u16 v2 = f2bf(acc[2] + bias), v3 = f2bf(acc[3] + bias);
    if (z == 0) {
        u16x4 pv = {v0, v1, v2, v3};
        *(u16x4*)&xpz[base + tt0] = pv;
    } else {
        u16x4 pv = {v3, v2, v1, v0};
        *(u16x4*)&xpz[base + 124 - tt0] = pv;
    }
}

// ---------------------------------------------------------------------------
// K3: bidirectional GRU, r15 version (best measured: 60.7 us).
// 16 blocks = (z, b), 512 thr (8 waves). Per step: broadcast A-frag ds_read,
// 12 chained MFMA/wave (n-tile triple {w,w+8,w+16}), gate on lanes<16, one
// raw barrier. hist 2-slot ring; chunked ushort8 xp prefetch.
// ---------------------------------------------------------------------------
__global__ __launch_bounds__(512)
void k3_gru(const u16* __restrict__ xp3,      // [2][3][128][8][128] bf16
            const float* __restrict__ whf, const float* __restrict__ bhf,
            const float* __restrict__ whb, const float* __restrict__ bhb,
            u16* __restrict__ hout)           // [2][8][128][128] bf16
{
    const int z   = blockIdx.x >> 3;
    const int b   = blockIdx.x & 7;           // batch
    const int tid = threadIdx.x;
    const int w   = tid >> 6;
    const int l   = tid & 63;
    const int nr  = l & 15;
    const int kb  = (l >> 4) * 8;
    const int gdim = w * 16 + (l & 15);       // gate hidden dim (valid l<16)

    __shared__ __align__(16) u16 hist[2][128];   // [slot][hidden] 512 B

    const float* W  = z ? whb : whf;
    const float* bh = z ? bhb : bhf;

    // W_hh B-frags (bf16) in VGPRs: wave w owns n-tiles {w, w+8, w+16}
    bf16x8 Whi[3][4];
    #pragma unroll
    for (int g = 0; g < 3; g++) {
        #pragma unroll
        for (int kt = 0; kt < 4; kt++) {
            const float* src = W + (size_t)(g * 128 + w * 16 + nr) * 128 + kt * 32 + kb;
            float4 w0 = *(const float4*)src;
            float4 w1 = *(const float4*)(src + 4);
            bf16x8 hi;
            hi[0] = (short)f2bf(w0.x); hi[1] = (short)f2bf(w0.y);
            hi[2] = (short)f2bf(w0.z); hi[3] = (short)f2bf(w0.w);
            hi[4] = (short)f2bf(w1.x); hi[5] = (short)f2bf(w1.y);
            hi[6] = (short)f2bf(w1.z); hi[7] = (short)f2bf(w1.w);
            Whi[g][kt] = hi;
        }
    }

    float br = 0.f, bz = 0.f, bn = 0.f;
    float hm = 0.f;
    const u16* xq = xp3 + (size_t)z * 393216;
    u16* ho = hout + (size_t)z * 131072 + (size_t)b * 16384;

    // chunked xp prefetch (gate lanes only)
    size_t bR = 0, bZ = 0, bN = 0;
    u16x8 cR = {0,0,0,0,0,0,0,0}, cZ = cR, cN = cR;   // current chunk
    u16x8 nR = cR, nZ = cR, nN = cR;                  // next chunk
    if (l < 16) {
        br = bh[gdim]; bz = bh[gdim + 128]; bn = bh[gdim + 256];
        bR = ((size_t)(0 * 128 + gdim) * 8 + b) * 128;
        bZ = ((size_t)(1 * 128 + gdim) * 8 + b) * 128;
        bN = ((size_t)(2 * 128 + gdim) * 8 + b) * 128;
        cR = *(const u16x8*)&xq[bR];      cZ = *(const u16x8*)&xq[bZ];      cN = *(const u16x8*)&xq[bN];
        nR = *(const u16x8*)&xq[bR + 8];  nZ = *(const u16x8*)&xq[bZ + 8];  nN = *(const u16x8*)&xq[bN + 8];
    }
    if (tid < 128) ((unsigned*)hist)[tid] = 0u;    // h = 0 (both slots)
    __syncthreads();

    const f32x4 z4 = {0.f, 0.f, 0.f, 0.f};

    for (int ch = 0; ch < 16; ch++) {
        #pragma unroll
        for (int s = 0; s < 8; s++) {
            const int c = ch * 8 + s;
            const int rslot = (c + 1) & 1, wslot = c & 1;

            // broadcast A-frag read (16-lane groups share an address)
            const u16* hb_ = &hist[rslot][kb];
            bf16x8 A0 = *(const bf16x8*)&hb_[0];
            bf16x8 A1 = *(const bf16x8*)&hb_[32];
            bf16x8 A2 = *(const bf16x8*)&hb_[64];
            bf16x8 A3 = *(const bf16x8*)&hb_[96];

            f32x4 a0 = z4, a1 = z4, a2 = z4;
            a0 = __builtin_amdgcn_mfma_f32_16x16x32_bf16(A0, Whi[0][0], a0, 0,0,0);
            a1 = __builtin_amdgcn_mfma_f32_16x16x32_bf16(A0, Whi[1][0], a1, 0,0,0);
            a2 = __builtin_amdgcn_mfma_f32_16x16x32_bf16(A0, Whi[2][0], a2, 0,0,0);
            a0 = __builtin_amdgcn_mfma_f32_16x16x32_bf16(A1, Whi[0][1], a0, 0,0,0);
            a1 = __builtin_amdgcn_mfma_f32_16x16x32_bf16(A1, Whi[1][1], a1, 0,0,0);
            a2 = __builtin_amdgcn_mfma_f32_16x16x32_bf16(A1, Whi[2][1], a2, 0,0,0);
            a0 = __builtin_amdgcn_mfma_f32_16x16x32_bf16(A2, Whi[0][2], a0, 0,0,0);
            a1 = __builtin_amdgcn_mfma_f32_16x16x32_bf16(A2, Whi[1][2], a1, 0,0,0);
            a2 = __builtin_amdgcn_mfma_f32_16x16x32_bf16(A2, Whi[2][2], a2, 0,0,0);
            a0 = __builtin_amdgcn_mfma_f32_16x16x32_bf16(A3, Whi[0][3], a0, 0,0,0);
            a1 = __builtin_amdgcn_mfma_f32_16x16x32_bf16(A3, Whi[1][3], a1, 0,0,0);
            a2 = __builtin_amdgcn_mfma_f32_16x16x32_bf16(A3, Whi[2][3], a2, 0,0,0);

            if (l < 16) {
                const int tw = z ? (127 - c) : c;
                float rr = sigm(bf2f((u16)cR[s]) + a0[0] + br);
                float zg = sigm(bf2f((u16)cZ[s]) + a1[0] + bz);
                float nn = tanh_fast(bf2f((u16)cN[s]) + rr * (a2[0] + bn));
                hm = (1.f - zg) * nn + zg * hm;
                u16 hb2 = f2bf(hm);
                hist[wslot][gdim] = hb2;
                ho[(size_t)tw * 128 + gdim] = hb2;
            }
            STEP_BAR();
        }
        // chunk boundary: rotate and issue loads for chunk ch+2
        if (l < 16) {
            cR = nR; cZ = nZ; cN = nN;
            if (ch < 14) {
                const size_t o = (size_t)(ch + 2) * 8;
                nR = *(const u16x8*)&xq[bR + o];
                nZ = *(const u16x8*)&xq[bZ + o];
                nN = *(const u16x8*)&xq[bN + o];
            }
        }
    }
}

// ---------------------------------------------------------------------------
// K4: MLP head. 1024 blocks = (b,t), 128 threads. (unchanged)
// ---------------------------------------------------------------------------
__global__ __launch_bounds__(128)
void k4_mlp(const u16* __restrict__ hout,
            const float* __restrict__ w1, const float* __restrict__ b1,
            const float* __restrict__ w2, const float* __restrict__ b2,
            float* __restrict__ out)
{
    const int bq  = blockIdx.x;
    const int tid = threadIdx.x;

    __shared__ __align__(16) float hrow[256];
    __shared__ float hid[50];

    const u16* hf = hout + (size_t)bq * 128;
    const u16* hb = hout + (size_t)8 * 128 * 128 + (size_t)bq * 128;
    hrow[tid]       = bf2f(hf[tid]);
    hrow[128 + tid] = bf2f(hb[tid]);
    __syncthreads();

    if (tid < 50) {
        float a = b1[tid];
        const float* wr = w1 + (size_t)tid * 256;
        for (int k0 = 0; k0 < 256; k0 += 8) {
            float4 wv0 = *(const float4*)&wr[k0];
            float4 wv1 = *(const float4*)&wr[k0 + 4];
            float4 h0  = *(const float4*)&hrow[k0];
            float4 h1  = *(const float4*)&hrow[k0 + 4];
            a += wv0.x * h0.x + wv0.y * h0.y + wv0.z * h0.z + wv0.w * h0.w;
            a += wv1.x * h1.x + wv1.y * h1.y + wv1.z * h1.z + wv1.w * h1.w;
        }
        hid[tid] = fmaxf(a, 0.f);
    }
    __syncthreads();
    if (tid < 64) {
        float a = b2[tid];
        const float* wr = w2 + (size_t)tid * 50;
        for (int k = 0; k < 50; k++) a += wr[k] * hid[k];
        out[(size_t)bq * 64 + tid] = a;
    }
}

// ---------------------------------------------------------------------------
// Workspace (2.4 MB):
//   [0,     512K)  : aout bf16 [1024][128] (k1m->K2), reused as hout (K3->K4)
//   [512K,  2.0M)  : xp3 bf16 (K2->K3, tau-innermost layout)
//   [2.0M,  2.375M): Wf bf16 [2][384][256] (k1m->K2)
//   [2.375M,+3K)   : Bf f32  [2][384]      (k1m->K2, upper-half folded)
// hout aliases aout: aout dead after K2; K3 reads only xp3 while writing.
// ---------------------------------------------------------------------------
extern "C" void kernel_launch(void* const* d_in, const int* in_sizes, int n_in,
                              void* d_out, int out_size, void* d_ws, size_t ws_size,
                              hipStream_t stream)
{
    const float* x    = (const float*)d_in[0];
    const float* ts   = (const float*)d_in[1];
    const float* qy   = (const float*)d_in[2];
    const float* bww  = (const float*)d_in[3];
    const float* cw   = (const float*)d_in[4];
    const float* cb   = (const float*)d_in[5];
    const float* wihf = (const float*)d_in[6];
    const float* whhf = (const float*)d_in[7];
    const float* bihf = (const float*)d_in[8];
    const float* bhhf = (const float*)d_in[9];
    const float* wihb = (const float*)d_in[10];
    const float* whhb = (const float*)d_in[11];
    const float* bihb = (const float*)d_in[12];
    const float* bhhb = (const float*)d_in[13];
    const float* w1   = (const float*)d_in[14];
    const float* b1   = (const float*)d_in[15];
    const float* w2   = (const float*)d_in[16];
    const float* b2   = (const float*)d_in[17];
    float* out = (float*)d_out;

    char* ws = (char*)d_ws;
    u16*   aout = (u16*)ws;                            // 256 KB used
    u16*   hout = (u16*)ws;                            // alias (aout dead after K2)
    u16*   xp3  = (u16*)(ws + (512 << 10));            // 1.5 MB
    u16*   Wf   = (u16*)(ws + (2u << 20));             // 384 KB
    float* Bf   = (float*)(ws + (2u << 20) + 384 * 1024);  // 3 KB

    k1m<<<448, 1024, 0, stream>>>(x, ts, qy, bww, wihf, bihf, wihb, bihb,
                                  cw, cb, aout, Wf, Bf);
    k2_xp<<<768, 256, 0, stream>>>(aout, Wf, Bf, xp3);
    k3_gru<<<16, 512, 0, stream>>>(xp3, whhf, bhhf, whhb, bhhb, hout);
    k4_mlp<<<1024, 128, 0, stream>>>(hout, w1, b1, w2, b2, out);
}

// Round 20
// 97.564 us; speedup vs baseline: 1.3405x; 1.1609x over previous
//
#include <hip/hip_runtime.h>

typedef unsigned short u16;
typedef __attribute__((ext_vector_type(8))) short bf16x8;
typedef __attribute__((ext_vector_type(4))) float f32x4;
typedef __attribute__((ext_vector_type(4))) unsigned short u16x4;
typedef __attribute__((ext_vector_type(8))) unsigned short u16x8;

#define LOG2E 1.4426950408889634f

__device__ __forceinline__ float bf2f(u16 v) {
    union { unsigned u; float f; } x; x.u = ((unsigned)v) << 16; return x.f;
}
__device__ __forceinline__ u16 f2bf(float f) {
    union { float f; unsigned u; } x; x.f = f;
    unsigned u = x.u;
    u += 0x7FFFu + ((u >> 16) & 1u);   // round-to-nearest-even
    return (u16)(u >> 16);
}
__device__ __forceinline__ float sigm(float x) {
    return __builtin_amdgcn_rcpf(1.f + __builtin_amdgcn_exp2f(-x * LOG2E));
}
__device__ __forceinline__ float tanh_fast(float y) {
    float e = __builtin_amdgcn_exp2f(y * (2.f * LOG2E));
    return 1.f - 2.f * __builtin_amdgcn_rcpf(e + 1.f);   // saturates to +-1 safely
}
// raw barrier: LDS visibility only, NO vmem drain
#define STEP_BAR() asm volatile("s_waitcnt lgkmcnt(0)\ns_barrier" ::: "memory")

// ---------------------------------------------------------------------------
// K1M v2: fused {attention lower-half} + {weight-fold}.
// Attention blocks 0..255: thread = (sh 0-7, d 0-127); each thread keeps
// FOUR (num,den) register pairs (one per q of the tile) over a 64-step
// s-range -> each x element is loaded ONCE per block (L2 traffic 537->134MB,
// was the envelope's L2-BW bottleneck). 8-group LDS reduction at the end.
// Weight-fold blocks 256..447: unchanged (r17/r19 version).
// ---------------------------------------------------------------------------
__global__ __launch_bounds__(1024)
void k1m(const float* __restrict__ x, const float* __restrict__ ts,
         const float* __restrict__ qy, const float* __restrict__ bww,
         const float* __restrict__ wihf, const float* __restrict__ bihf,
         const float* __restrict__ wihb, const float* __restrict__ bihb,
         const float* __restrict__ cw, const float* __restrict__ cb,
         u16* __restrict__ aout, u16* __restrict__ Wf, float* __restrict__ Bf)
{
    __shared__ float red[8][8][128];   // [sh][num0-3,den0-3 -> 8][d] 32 KB
    __shared__ float red0[4][256];
    const int tid = threadIdx.x;

    if (blockIdx.x < 256) {
        // ---------------- attention (lower half only) ----------------
        const int b  = blockIdx.x >> 5;
        const int q0 = (blockIdx.x & 31) * 4;
        const int d  = tid & 127;
        const int sh = tid >> 7;            // 0..7

        float w  = bww[d];
        float kk = log1pf(expf(w)) * LOG2E;
        float qv0 = qy[q0 + 0], qv1 = qy[q0 + 1];
        float qv2 = qy[q0 + 2], qv3 = qy[q0 + 3];
        float A0 = -kk * qv0 * qv0, B0 = 2.f * kk * qv0;
        float A1 = -kk * qv1 * qv1, B1 = 2.f * kk * qv1;
        float A2 = -kk * qv2 * qv2, B2 = 2.f * kk * qv2;
        float A3 = -kk * qv3 * qv3, B3 = 2.f * kk * qv3;
        float C  = -kk;

        const float* xb = x + (size_t)b * 512 * 256;
        const float* tb = ts + b * 512;

        float n0 = 0.f, n1 = 0.f, n2 = 0.f, n3 = 0.f;
        float d0 = 0.f, d1 = 0.f, d2 = 0.f, d3 = 0.f;
        const int s0 = sh * 64;
        #pragma unroll 4
        for (int s = s0; s < s0 + 64; s++) {
            float xv = xb[(size_t)s * 256 + d];          // vals*mask (1 load)
            float mv = xb[(size_t)s * 256 + 128 + d];    // mask      (1 load)
            float t  = tb[s];                            // uniform -> s_load
            float ct  = C * t;
            float mxv = mv * xv;
            float p0 = __builtin_amdgcn_exp2f(A0 + t * (B0 + ct));
            float p1 = __builtin_amdgcn_exp2f(A1 + t * (B1 + ct));
            float p2 = __builtin_amdgcn_exp2f(A2 + t * (B2 + ct));
            float p3 = __builtin_amdgcn_exp2f(A3 + t * (B3 + ct));
            n0 += p0 * mxv;  d0 += p0 * mv;
            n1 += p1 * mxv;  d1 += p1 * mv;
            n2 += p2 * mxv;  d2 += p2 * mv;
            n3 += p3 * mxv;  d3 += p3 * mv;
        }
        red[sh][0][d] = n0;  red[sh][1][d] = n1;
        red[sh][2][d] = n2;  red[sh][3][d] = n3;
        red[sh][4][d] = d0;  red[sh][5][d] = d1;
        red[sh][6][d] = d2;  red[sh][7][d] = d3;
        __syncthreads();
        if (tid < 512) {
            const int qq = tid >> 7;
            const int dd = tid & 127;
            float num = 0.f, den = 0.f;
            #pragma unroll
            for (int g = 0; g < 8; g++) {
                num += red[g][qq][dd];
                den += red[g][4 + qq][dd];
            }
            aout[(size_t)(b * 128 + q0 + qq) * 128 + dd] = f2bf(num / fmaxf(den, 1e-30f));
        }
    } else {
        // ---------------- weight fold ----------------
        const int bk = blockIdx.x - 256;
        const int z  = bk / 96;
        const int n0 = (bk % 96) * 4;
        const int i  = tid >> 8;       // row 0..3
        const int j  = tid & 255;
        const float* W   = z ? wihb : wihf;
        const float* bih = z ? bihb : bihf;

        float a = 0.f;
        const float* wr = W + (size_t)(n0 + i) * 256;
        for (int k = 0; k < 256; k++)
            a += wr[k] * cw[(size_t)k * 256 + j];
        u16 wb = f2bf(a);
        Wf[((size_t)z * 384 + n0 + i) * 256 + j] = wb;

        float up = (j >= 128) ? bf2f(wb) : 0.f;
        red0[i][j] = wr[j] * cb[j] + up;
        __syncthreads();
        if (j < 64) red0[i][j] += red0[i][j + 64] + red0[i][j + 128] + red0[i][j + 192];
        __syncthreads();
        if (j == 0) {
            float s = 0.f;
            for (int t2 = 0; t2 < 64; t2++) s += red0[i][t2];
            Bf[z * 384 + n0 + i] = s + bih[n0 + i];
        }
    }
}

// ---------------------------------------------------------------------------
// K2: xp3 = aout @ Wf[:,0:128]^T + Bf via MFMA (K=128). (unchanged)
// XP3[z][g][dim][b][tau] layout, tau = (z ? 127-t : t).
// ---------------------------------------------------------------------------
__global__ __launch_bounds__(256)
void k2_xp(const u16* __restrict__ aout,
           const u16* __restrict__ Wf, const float* __restrict__ Bf,
           u16* __restrict__ xp3)    // [2][3][128][8][128] bf16
{
    const int wid  = threadIdx.x >> 6;
    const int lane = threadIdx.x & 63;
    int gw = blockIdx.x * 4 + wid;
    int z  = (gw >= 1536) ? 1 : 0;
    int t  = gw - z * 1536;
    int rt = t / 24, nt = t - rt * 24;
    int r0 = rt * 16, n0 = nt * 16;

    const u16*   W  = Wf + (size_t)z * 384 * 256;
    const float* Bv = Bf + z * 384;

    const u16* arow = aout + (size_t)(r0 + (lane & 15)) * 128 + (lane >> 4) * 8;
    const u16* brow = W    + (size_t)(n0 + (lane & 15)) * 256 + (lane >> 4) * 8;

    f32x4 acc = {0.f, 0.f, 0.f, 0.f};
    #pragma unroll
    for (int k = 0; k < 4; k++) {
        bf16x8 a     = *(const bf16x8*)(arow + k * 32);
        bf16x8 bfrag = *(const bf16x8*)(brow + k * 32);
        acc = __builtin_amdgcn_mfma_f32_16x16x32_bf16(a, bfrag, acc, 0, 0, 0);
    }
    int col   = n0 + (lane & 15);
    int rbase = r0 + (lane >> 4) * 4;
    float bias = Bv[col];
    int g   = col >> 7;
    int dv  = col & 127;
    int bb  = rbase >> 7;
    int tt0 = rbase & 127;
    u16* xpz = xp3 + (size_t)z * 393216;
    size_t base = ((size_t)(g * 128 + dv) * 8 + bb) * 128;
    u16 v0 = f2bf(acc[0] + bias), v1 = f2bf(acc[1] + bias);
    u16 v2 = f2bf(acc[2] + bias), v3 = f2bf(acc[3] + bias);
    if (z == 0) {
        u16x4 pv = {v0, v1, v2, v3};
        *(u16x4*)&xpz[base + tt0] = pv;
    } else {
        u16x4 pv = {v3, v2, v1, v0};
        *(u16x4*)&xpz[base + 124 - tt0] = pv;
    }
}

// ---------------------------------------------------------------------------
// K3: bidirectional GRU, r15 version (best measured: 60.0 us). (unchanged)
// ---------------------------------------------------------------------------
__global__ __launch_bounds__(512)
void k3_gru(const u16* __restrict__ xp3,      // [2][3][128][8][128] bf16
            const float* __restrict__ whf, const float* __restrict__ bhf,
            const float* __restrict__ whb, const float* __restrict__ bhb,
            u16* __restrict__ hout)           // [2][8][128][128] bf16
{
    const int z   = blockIdx.x >> 3;
    const int b   = blockIdx.x & 7;           // batch
    const int tid = threadIdx.x;
    const int w   = tid >> 6;
    const int l   = tid & 63;
    const int nr  = l & 15;
    const int kb  = (l >> 4) * 8;
    const int gdim = w * 16 + (l & 15);       // gate hidden dim (valid l<16)

    __shared__ __align__(16) u16 hist[2][128];   // [slot][hidden] 512 B

    const float* W  = z ? whb : whf;
    const float* bh = z ? bhb : bhf;

    // W_hh B-frags (bf16) in VGPRs: wave w owns n-tiles {w, w+8, w+16}
    bf16x8 Whi[3][4];
    #pragma unroll
    for (int g = 0; g < 3; g++) {
        #pragma unroll
        for (int kt = 0; kt < 4; kt++) {
            const float* src = W + (size_t)(g * 128 + w * 16 + nr) * 128 + kt * 32 + kb;
            float4 w0 = *(const float4*)src;
            float4 w1 = *(const float4*)(src + 4);
            bf16x8 hi;
            hi[0] = (short)f2bf(w0.x); hi[1] = (short)f2bf(w0.y);
            hi[2] = (short)f2bf(w0.z); hi[3] = (short)f2bf(w0.w);
            hi[4] = (short)f2bf(w1.x); hi[5] = (short)f2bf(w1.y);
            hi[6] = (short)f2bf(w1.z); hi[7] = (short)f2bf(w1.w);
            Whi[g][kt] = hi;
        }
    }

    float br = 0.f, bz = 0.f, bn = 0.f;
    float hm = 0.f;
    const u16* xq = xp3 + (size_t)z * 393216;
    u16* ho = hout + (size_t)z * 131072 + (size_t)b * 16384;

    // chunked xp prefetch (gate lanes only)
    size_t bR = 0, bZ = 0, bN = 0;
    u16x8 cR = {0,0,0,0,0,0,0,0}, cZ = cR, cN = cR;   // current chunk
    u16x8 nR = cR, nZ = cR, nN = cR;                  // next chunk
    if (l < 16) {
        br = bh[gdim]; bz = bh[gdim + 128]; bn = bh[gdim + 256];
        bR = ((size_t)(0 * 128 + gdim) * 8 + b) * 128;
        bZ = ((size_t)(1 * 128 + gdim) * 8 + b) * 128;
        bN = ((size_t)(2 * 128 + gdim) * 8 + b) * 128;
        cR = *(const u16x8*)&xq[bR];      cZ = *(const u16x8*)&xq[bZ];      cN = *(const u16x8*)&xq[bN];
        nR = *(const u16x8*)&xq[bR + 8];  nZ = *(const u16x8*)&xq[bZ + 8];  nN = *(const u16x8*)&xq[bN + 8];
    }
    if (tid < 128) ((unsigned*)hist)[tid] = 0u;    // h = 0 (both slots)
    __syncthreads();

    const f32x4 z4 = {0.f, 0.f, 0.f, 0.f};

    for (int ch = 0; ch < 16; ch++) {
        #pragma unroll
        for (int s = 0; s < 8; s++) {
            const int c = ch * 8 + s;
            const int rslot = (c + 1) & 1, wslot = c & 1;

            // broadcast A-frag read (16-lane groups share an address)
            const u16* hb_ = &hist[rslot][kb];
            bf16x8 A0 = *(const bf16x8*)&hb_[0];
            bf16x8 A1 = *(const bf16x8*)&hb_[32];
            bf16x8 A2 = *(const bf16x8*)&hb_[64];
            bf16x8 A3 = *(const bf16x8*)&hb_[96];

            f32x4 a0 = z4, a1 = z4, a2 = z4;
            a0 = __builtin_amdgcn_mfma_f32_16x16x32_bf16(A0, Whi[0][0], a0, 0,0,0);
            a1 = __builtin_amdgcn_mfma_f32_16x16x32_bf16(A0, Whi[1][0], a1, 0,0,0);
            a2 = __builtin_amdgcn_mfma_f32_16x16x32_bf16(A0, Whi[2][0], a2, 0,0,0);
            a0 = __builtin_amdgcn_mfma_f32_16x16x32_bf16(A1, Whi[0][1], a0, 0,0,0);
            a1 = __builtin_amdgcn_mfma_f32_16x16x32_bf16(A1, Whi[1][1], a1, 0,0,0);
            a2 = __builtin_amdgcn_mfma_f32_16x16x32_bf16(A1, Whi[2][1], a2, 0,0,0);
            a0 = __builtin_amdgcn_mfma_f32_16x16x32_bf16(A2, Whi[0][2], a0, 0,0,0);
            a1 = __builtin_amdgcn_mfma_f32_16x16x32_bf16(A2, Whi[1][2], a1, 0,0,0);
            a2 = __builtin_amdgcn_mfma_f32_16x16x32_bf16(A2, Whi[2][2], a2, 0,0,0);
            a0 = __builtin_amdgcn_mfma_f32_16x16x32_bf16(A3, Whi[0][3], a0, 0,0,0);
            a1 = __builtin_amdgcn_mfma_f32_16x16x32_bf16(A3, Whi[1][3], a1, 0,0,0);
            a2 = __builtin_amdgcn_mfma_f32_16x16x32_bf16(A3, Whi[2][3], a2, 0,0,0);

            if (l < 16) {
                const int tw = z ? (127 - c) : c;
                float rr = sigm(bf2f((u16)cR[s]) + a0[0] + br);
                float zg = sigm(bf2f((u16)cZ[s]) + a1[0] + bz);
                float nn = tanh_fast(bf2f((u16)cN[s]) + rr * (a2[0] + bn));
                hm = (1.f - zg) * nn + zg * hm;
                u16 hb2 = f2bf(hm);
                hist[wslot][gdim] = hb2;
                ho[(size_t)tw * 128 + gdim] = hb2;
            }
            STEP_BAR();
        }
        // chunk boundary: rotate and issue loads for chunk ch+2
        if (l < 16) {
            cR = nR; cZ = nZ; cN = nN;
            if (ch < 14) {
                const size_t o = (size_t)(ch + 2) * 8;
                nR = *(const u16x8*)&xq[bR + o];
                nZ = *(const u16x8*)&xq[bZ + o];
                nN = *(const u16x8*)&xq[bN + o];
            }
        }
    }
}

// ---------------------------------------------------------------------------
// K4: MLP head. 1024 blocks = (b,t), 128 threads. (unchanged)
// ---------------------------------------------------------------------------
__global__ __launch_bounds__(128)
void k4_mlp(const u16* __restrict__ hout,
            const float* __restrict__ w1, const float* __restrict__ b1,
            const float* __restrict__ w2, const float* __restrict__ b2,
            float* __restrict__ out)
{
    const int bq  = blockIdx.x;
    const int tid = threadIdx.x;

    __shared__ __align__(16) float hrow[256];
    __shared__ float hid[50];

    const u16* hf = hout + (size_t)bq * 128;
    const u16* hb = hout + (size_t)8 * 128 * 128 + (size_t)bq * 128;
    hrow[tid]       = bf2f(hf[tid]);
    hrow[128 + tid] = bf2f(hb[tid]);
    __syncthreads();

    if (tid < 50) {
        float a = b1[tid];
        const float* wr = w1 + (size_t)tid * 256;
        for (int k0 = 0; k0 < 256; k0 += 8) {
            float4 wv0 = *(const float4*)&wr[k0];
            float4 wv1 = *(const float4*)&wr[k0 + 4];
            float4 h0  = *(const float4*)&hrow[k0];
            float4 h1  = *(const float4*)&hrow[k0 + 4];
            a += wv0.x * h0.x + wv0.y * h0.y + wv0.z * h0.z + wv0.w * h0.w;
            a += wv1.x * h1.x + wv1.y * h1.y + wv1.z * h1.z + wv1.w * h1.w;
        }
        hid[tid] = fmaxf(a, 0.f);
    }
    __syncthreads();
    if (tid < 64) {
        float a = b2[tid];
        const float* wr = w2 + (size_t)tid * 50;
        for (int k = 0; k < 50; k++) a += wr[k] * hid[k];
        out[(size_t)bq * 64 + tid] = a;
    }
}

// ---------------------------------------------------------------------------
// Workspace (2.4 MB):
//   [0,     512K)  : aout bf16 [1024][128] (k1m->K2), reused as hout (K3->K4)
//   [512K,  2.0M)  : xp3 bf16 (K2->K3, tau-innermost layout)
//   [2.0M,  2.375M): Wf bf16 [2][384][256] (k1m->K2)
//   [2.375M,+3K)   : Bf f32  [2][384]      (k1m->K2, upper-half folded)
// hout aliases aout: aout dead after K2; K3 reads only xp3 while writing.
// ---------------------------------------------------------------------------
extern "C" void kernel_launch(void* const* d_in, const int* in_sizes, int n_in,
                              void* d_out, int out_size, void* d_ws, size_t ws_size,
                              hipStream_t stream)
{
    const float* x    = (const float*)d_in[0];
    const float* ts   = (const float*)d_in[1];
    const float* qy   = (const float*)d_in[2];
    const float* bww  = (const float*)d_in[3];
    const float* cw   = (const float*)d_in[4];
    const float* cb   = (const float*)d_in[5];
    const float* wihf = (const float*)d_in[6];
    const float* whhf = (const float*)d_in[7];
    const float* bihf = (const float*)d_in[8];
    const float* bhhf = (const float*)d_in[9];
    const float* wihb = (const float*)d_in[10];
    const float* whhb = (const float*)d_in[11];
    const float* bihb = (const float*)d_in[12];
    const float* bhhb = (const float*)d_in[13];
    const float* w1   = (const float*)d_in[14];
    const float* b1   = (const float*)d_in[15];
    const float* w2   = (const float*)d_in[16];
    const float* b2   = (const float*)d_in[17];
    float* out = (float*)d_out;

    char* ws = (char*)d_ws;
    u16*   aout = (u16*)ws;                            // 256 KB used
    u16*   hout = (u16*)ws;                            // alias (aout dead after K2)
    u16*   xp3  = (u16*)(ws + (512 << 10));            // 1.5 MB
    u16*   Wf   = (u16*)(ws + (2u << 20));             // 384 KB
    float* Bf   = (float*)(ws + (2u << 20) + 384 * 1024);  // 3 KB

    k1m<<<448, 1024, 0, stream>>>(x, ts, qy, bww, wihf, bihf, wihb, bihb,
                                  cw, cb, aout, Wf, Bf);
    k2_xp<<<768, 256, 0, stream>>>(aout, Wf, Bf, xp3);
    k3_gru<<<16, 512, 0, stream>>>(xp3, whhf, bhhf, whhb, bhhb, hout);
    k4_mlp<<<1024, 128, 0, stream>>>(hout, w1, b1, w2, b2, out);
}